// Round 9
// baseline (72.539 us; speedup 1.0000x reference)
//
#include <hip/hip_runtime.h>
#include <hip/hip_bf16.h>

#define B_   4
#define N_   8192
#define CIN_ 64
#define H_   8
#define HD_  512
#define EPS_ 1e-5f
#define NCW_ 64            // wave-tasks per (b,h): 64 chunks x 128 rows
#define MT_SCALE 1024.0f   // power-of-2: keeps fp16 Mt away from subnormals

typedef _Float16 f16x8 __attribute__((ext_vector_type(8)));
typedef _Float16 f16x4 __attribute__((ext_vector_type(4)));
typedef float    f32x4 __attribute__((ext_vector_type(4)));

// ---------------- workspace layout ----------------
constexpr size_t OFF_V    = 0;
constexpr size_t SZ_V     = (size_t)B_ * N_ * CIN_ * 2;           // 4 MB f16 v
constexpr size_t OFF_WQ   = OFF_V + SZ_V;
constexpr size_t SZ_W     = (size_t)HD_ * CIN_ * 2;               // 64 KB each
constexpr size_t OFF_WK   = OFF_WQ + SZ_W;
constexpr size_t OFF_WV   = OFF_WK + SZ_W;
constexpr size_t OFF_MT   = OFF_WV + SZ_W;
constexpr size_t SZ_MT    = (size_t)B_ * 64 * HD_ * 2;            // 256 KB f16 Mt
constexpr size_t OFF_KVG  = OFF_MT + SZ_MT;
constexpr size_t SZ_KVG   = (size_t)B_ * H_ * 4096 * 4;           // 512 KB fp32
constexpr size_t OFF_PART = OFF_KVG + SZ_KVG;
constexpr size_t SZ_PART  = (size_t)B_ * H_ * NCW_ * 4096 * 4;    // 32 MB fp32
constexpr size_t WS_NEED  = OFF_PART + SZ_PART;

// ---------------- prep: all fp32->fp16 casts in one kernel ----------------
__global__ __launch_bounds__(256) void prep_cast(
    const float* __restrict__ v, const float* __restrict__ wq,
    const float* __restrict__ wk, const float* __restrict__ wv,
    _Float16* __restrict__ vb, _Float16* __restrict__ wqb,
    _Float16* __restrict__ wkb, _Float16* __restrict__ wvb) {
  const int NV4 = B_ * N_ * CIN_ / 4;   // 524288
  const int NW4 = HD_ * CIN_ / 4;       // 8192
  int i = blockIdx.x * 256 + threadIdx.x;  // grid sized exactly
  const float* src; _Float16* dst; int j;
  if (i < NV4)                { src = v;  dst = vb;  j = i; }
  else if (i < NV4 + NW4)     { src = wq; dst = wqb; j = i - NV4; }
  else if (i < NV4 + 2 * NW4) { src = wk; dst = wkb; j = i - NV4 - NW4; }
  else                        { src = wv; dst = wvb; j = i - NV4 - 2 * NW4; }
  const float4 f = reinterpret_cast<const float4*>(src)[j];
  f16x4 o;
  o[0] = (_Float16)f.x; o[1] = (_Float16)f.y; o[2] = (_Float16)f.z; o[3] = (_Float16)f.w;
  reinterpret_cast<f16x4*>(dst)[j] = o;
}

// ---------------- K1: R1 structure — INDEPENDENT waves ----------------------
// Each wave = R1's old block: own 18432B LDS region, own 128-row chunk
// (2 tiles of 64), writes its OWN partial. No cross-wave data sharing at all.
// 4 waves/block purely for launch efficiency; barriers are uniform.
__global__ __launch_bounds__(256, 2) void k1_kv(
    const _Float16* __restrict__ vb, const _Float16* __restrict__ wkb,
    const _Float16* __restrict__ wvb, const float* __restrict__ kbias,
    const float* __restrict__ vbias, const float* __restrict__ lnkw,
    const float* __restrict__ lnkb, float* __restrict__ part) {
  const int ch = blockIdx.x, h = blockIdx.y, b = blockIdx.z;
  const int tid = threadIdx.x, w = tid >> 6, lane = tid & 63;
  const int l15 = lane & 15, g = lane >> 4;
  __shared__ alignas(16) char smem[73728];
  _Float16 (*Kt)[72] = reinterpret_cast<_Float16(*)[72]>(smem + w * 18432);        // [d][n]
  _Float16 (*Vt)[72] = reinterpret_cast<_Float16(*)[72]>(smem + w * 18432 + 9216); // [e][n]
  const int cw = ch * 4 + w;  // wave task 0..63

  const f32x4 z4 = {0.f, 0.f, 0.f, 0.f};
  f32x4 kv[4][4];
#pragma unroll
  for (int i = 0; i < 4; ++i)
#pragma unroll
    for (int j = 0; j < 4; ++j) kv[i][j] = z4;

  float kb[4], vbi[4], lw[4], lb[4];
#pragma unroll
  for (int c = 0; c < 4; ++c) {
    const int col = h * 64 + c * 16 + l15;
    kb[c] = kbias[col]; vbi[c] = vbias[col];
    lw[c] = lnkw[col];  lb[c] = lnkb[col];
  }
  f16x8 wkf[4][2], wvf[4][2];
#pragma unroll
  for (int c = 0; c < 4; ++c)
#pragma unroll
    for (int kk = 0; kk < 2; ++kk) {
      wkf[c][kk] = *reinterpret_cast<const f16x8*>(
          wkb + (size_t)(h * 64 + c * 16 + l15) * CIN_ + kk * 32 + g * 8);
      wvf[c][kk] = *reinterpret_cast<const f16x8*>(
          wvb + (size_t)(h * 64 + c * 16 + l15) * CIN_ + kk * 32 + g * 8);
    }

  for (int t = 0; t < 2; ++t) {
    const int row0 = cw * 128 + t * 64;
    f16x8 av[4][2];
#pragma unroll
    for (int m = 0; m < 4; ++m)
#pragma unroll
      for (int kk = 0; kk < 2; ++kk)
        av[m][kk] = *reinterpret_cast<const f16x8*>(
            vb + ((size_t)b * N_ + row0 + m * 16 + l15) * CIN_ + kk * 32 + g * 8);

    // ---- K proj + bias + LN -> Kt (m-pairs to cap VGPR) ----
#pragma unroll
    for (int mp = 0; mp < 2; ++mp) {
      f32x4 acc[2][4];
#pragma unroll
      for (int mi = 0; mi < 2; ++mi)
#pragma unroll
        for (int c = 0; c < 4; ++c) {
          f32x4 a = z4;
          a = __builtin_amdgcn_mfma_f32_16x16x32_f16(av[mp * 2 + mi][0], wkf[c][0], a, 0, 0, 0);
          a = __builtin_amdgcn_mfma_f32_16x16x32_f16(av[mp * 2 + mi][1], wkf[c][1], a, 0, 0, 0);
          acc[mi][c] = a;
        }
#pragma unroll
      for (int mi = 0; mi < 2; ++mi) {
        const int m = mp * 2 + mi;
        float s[4] = {0, 0, 0, 0}, ss[4] = {0, 0, 0, 0};
#pragma unroll
        for (int c = 0; c < 4; ++c)
#pragma unroll
          for (int r = 0; r < 4; ++r) {
            float x = acc[mi][c][r] + kb[c];
            acc[mi][c][r] = x;
            s[r] += x; ss[r] += x * x;
          }
#pragma unroll
        for (int r = 0; r < 4; ++r) {
#pragma unroll
          for (int off = 1; off < 16; off <<= 1) {
            s[r]  += __shfl_xor(s[r], off);
            ss[r] += __shfl_xor(ss[r], off);
          }
          const float mu   = s[r] * (1.f / 64.f);
          const float var  = ss[r] * (1.f / 64.f) - mu * mu;
          const float rstd = rsqrtf(var + EPS_);
#pragma unroll
          for (int c = 0; c < 4; ++c)
            acc[mi][c][r] = (acc[mi][c][r] - mu) * rstd * lw[c] + lb[c];
        }
#pragma unroll
        for (int c = 0; c < 4; ++c) {
          f16x4 p;
#pragma unroll
          for (int r = 0; r < 4; ++r) p[r] = (_Float16)acc[mi][c][r];
          *reinterpret_cast<f16x4*>(&Kt[c * 16 + l15][m * 16 + g * 4]) = p;
        }
      }
    }
    // ---- V proj + bias -> Vt ----
#pragma unroll
    for (int mp = 0; mp < 2; ++mp) {
      f32x4 acc[2][4];
#pragma unroll
      for (int mi = 0; mi < 2; ++mi)
#pragma unroll
        for (int c = 0; c < 4; ++c) {
          f32x4 a = z4;
          a = __builtin_amdgcn_mfma_f32_16x16x32_f16(av[mp * 2 + mi][0], wvf[c][0], a, 0, 0, 0);
          a = __builtin_amdgcn_mfma_f32_16x16x32_f16(av[mp * 2 + mi][1], wvf[c][1], a, 0, 0, 0);
          acc[mi][c] = a;
        }
#pragma unroll
      for (int mi = 0; mi < 2; ++mi) {
        const int m = mp * 2 + mi;
#pragma unroll
        for (int c = 0; c < 4; ++c) {
          f16x4 p;
#pragma unroll
          for (int r = 0; r < 4; ++r) p[r] = (_Float16)(acc[mi][c][r] + vbi[c]);
          *reinterpret_cast<f16x4*>(&Vt[c * 16 + l15][m * 16 + g * 4]) = p;
        }
      }
    }

    __syncthreads();  // LDS writes -> reads (own-wave data; barrier for ordering)

    // ---- KV accumulate (reads ONLY this wave's Kt/Vt) ----
    f16x8 va[4][2];
#pragma unroll
    for (int et = 0; et < 4; ++et)
#pragma unroll
      for (int nk = 0; nk < 2; ++nk)
        va[et][nk] = *reinterpret_cast<const f16x8*>(&Vt[et * 16 + l15][nk * 32 + g * 8]);
#pragma unroll
    for (int dt = 0; dt < 4; ++dt) {
      f16x8 ka[2];
#pragma unroll
      for (int nk = 0; nk < 2; ++nk)
        ka[nk] = *reinterpret_cast<const f16x8*>(&Kt[dt * 16 + l15][nk * 32 + g * 8]);
#pragma unroll
      for (int et = 0; et < 4; ++et) {
        kv[dt][et] = __builtin_amdgcn_mfma_f32_16x16x32_f16(ka[0], va[et][0], kv[dt][et], 0, 0, 0);
        kv[dt][et] = __builtin_amdgcn_mfma_f32_16x16x32_f16(ka[1], va[et][1], kv[dt][et], 0, 0, 0);
      }
    }

    __syncthreads();  // reads drained before next t's writes
  }

  // ---- per-wave partial store, [d][e] layout (R1 exact) ----
  float* p0 = part + (size_t)((b * H_ + h) * NCW_ + cw) * 4096;
#pragma unroll
  for (int dt = 0; dt < 4; ++dt)
#pragma unroll
    for (int et = 0; et < 4; ++et)
#pragma unroll
      for (int r = 0; r < 4; ++r)
        p0[(dt * 16 + g * 4 + r) * 64 + et * 16 + l15] = kv[dt][et][r];
}

// ---------------- K2a: parallel tree-reduce partials -> KVg ----------------
__global__ __launch_bounds__(256) void k2a_reduce(const float* __restrict__ part,
                                                 float* __restrict__ KVg) {
  const int s = blockIdx.x, h = blockIdx.y, b = blockIdx.z;  // s: 0..15
  const int idx = s * 256 + threadIdx.x;
  const float* p0 = part + (size_t)((b * H_ + h) * NCW_) * 4096 + idx;
  float acc = 0.f;
#pragma unroll 8
  for (int ch = 0; ch < NCW_; ++ch) acc += p0[(size_t)ch * 4096];
  KVg[(size_t)(b * H_ + h) * 4096 + idx] = acc;
}

// ---- K2b: Mt[b][E][h*64+d] = MT_SCALE*(KV @ ow_h^T)[d,E]/N  (f16) ----------
__global__ __launch_bounds__(256) void k2b_mt(const float* __restrict__ KVg,
                                              const float* __restrict__ ow,
                                              _Float16* __restrict__ Mt) {
  const int z = blockIdx.x, h = blockIdx.y, b = blockIdx.z;  // z: 16-row E-slice
  const int tid = threadIdx.x;
  __shared__ float KV[4096];       // [d][e]
  __shared__ float OW[16][65];
  const float* kv0 = KVg + (size_t)(b * H_ + h) * 4096;
  for (int i = tid; i < 4096; i += 256) KV[i] = kv0[i];
  for (int i = tid; i < 16 * 64; i += 256) {
    int E = i >> 6, c = i & 63;
    OW[E][c] = ow[(size_t)(z * 16 + E) * HD_ + h * 64 + c];
  }
  __syncthreads();
  for (int i = tid; i < 1024; i += 256) {
    const int d = i >> 4, e = i & 15;
    float s = 0.f;
#pragma unroll
    for (int c = 0; c < 64; ++c) s += KV[d * 64 + c] * OW[e][c];
    Mt[(size_t)(b * 64 + z * 16 + e) * HD_ + h * 64 + d] =
        (_Float16)(s * (MT_SCALE / N_));
  }
}

// ---------------- K3: R1 orientation — out = LN(Q) @ Mt^T + o_b/N -----------
__global__ __launch_bounds__(256, 2) void k3_out(
    const _Float16* __restrict__ vb, const _Float16* __restrict__ wqb,
    const float* __restrict__ qbias, const float* __restrict__ lnqw,
    const float* __restrict__ lnqb, const _Float16* __restrict__ Mt,
    const float* __restrict__ obias, float* __restrict__ out) {
  const int nt = blockIdx.x, b = blockIdx.y;
  const int tid = threadIdx.x, w = tid >> 6, lane = tid & 63;
  const int l15 = lane & 15, g = lane >> 4;
  __shared__ _Float16 Qt[64][520];  // [n][j]
  const int row0 = nt * 64;
  const f32x4 z4 = {0.f, 0.f, 0.f, 0.f};

  // v as A-frags: lane = n-row, k = cin contiguous (normal orientation)
  f16x8 av[4][2];
#pragma unroll
  for (int m = 0; m < 4; ++m)
#pragma unroll
    for (int kk = 0; kk < 2; ++kk)
      av[m][kk] = *reinterpret_cast<const f16x8*>(
          vb + ((size_t)b * N_ + row0 + m * 16 + l15) * CIN_ + kk * 32 + g * 8);

#pragma unroll
  for (int hh = 0; hh < 2; ++hh) {
    const int h = w * 2 + hh;
    f16x8 bf[4][2];  // Wq rows as B-frags
#pragma unroll
    for (int c = 0; c < 4; ++c)
#pragma unroll
      for (int kk = 0; kk < 2; ++kk)
        bf[c][kk] = *reinterpret_cast<const f16x8*>(
            wqb + (size_t)(h * 64 + c * 16 + l15) * CIN_ + kk * 32 + g * 8);
    float qb[4], lw[4], lb[4];
#pragma unroll
    for (int c = 0; c < 4; ++c) {
      const int col = h * 64 + c * 16 + l15;
      qb[c] = qbias[col]; lw[c] = lnqw[col]; lb[c] = lnqb[col];
    }
    f32x4 acc[4][4];
#pragma unroll
    for (int m = 0; m < 4; ++m)
#pragma unroll
      for (int c = 0; c < 4; ++c) {
        f32x4 a = z4;
        a = __builtin_amdgcn_mfma_f32_16x16x32_f16(av[m][0], bf[c][0], a, 0, 0, 0);
        a = __builtin_amdgcn_mfma_f32_16x16x32_f16(av[m][1], bf[c][1], a, 0, 0, 0);
        acc[m][c] = a;
      }
    // bias + LN over j (own 4 c-values + 16-lane butterfly), per row n
#pragma unroll
    for (int m = 0; m < 4; ++m) {
      float s[4] = {0, 0, 0, 0}, ss[4] = {0, 0, 0, 0};
#pragma unroll
      for (int c = 0; c < 4; ++c)
#pragma unroll
        for (int r = 0; r < 4; ++r) {
          float x = acc[m][c][r] + qb[c];
          acc[m][c][r] = x;
          s[r] += x; ss[r] += x * x;
        }
#pragma unroll
      for (int r = 0; r < 4; ++r) {
#pragma unroll
        for (int off = 1; off < 16; off <<= 1) {
          s[r]  += __shfl_xor(s[r], off);
          ss[r] += __shfl_xor(ss[r], off);
        }
        const float mu   = s[r] * (1.f / 64.f);
        const float var  = ss[r] * (1.f / 64.f) - mu * mu;
        const float rstd = rsqrtf(var + EPS_);
#pragma unroll
        for (int c = 0; c < 4; ++c)
          acc[m][c][r] = (acc[m][c][r] - mu) * rstd * lw[c] + lb[c];
      }
#pragma unroll
      for (int c = 0; c < 4; ++c)
#pragma unroll
        for (int r = 0; r < 4; ++r)
          Qt[m * 16 + g * 4 + r][h * 64 + c * 16 + l15] = (_Float16)acc[m][c][r];
    }
  }
  __syncthreads();

  // final GEMM: out[64 x 64] = Qt[64 x 512] @ Mt[b]^T  (R1 exact)
  f32x4 acc2[4];
#pragma unroll
  for (int et = 0; et < 4; ++et) acc2[et] = z4;
  for (int kk = 0; kk < 16; ++kk) {
    f16x8 aq = *reinterpret_cast<const f16x8*>(&Qt[w * 16 + l15][kk * 32 + g * 8]);
#pragma unroll
    for (int et = 0; et < 4; ++et) {
      f16x8 bm = *reinterpret_cast<const f16x8*>(
          Mt + (size_t)(b * 64 + et * 16 + l15) * HD_ + kk * 32 + g * 8);
      acc2[et] = __builtin_amdgcn_mfma_f32_16x16x32_f16(aq, bm, acc2[et], 0, 0, 0);
    }
  }
#pragma unroll
  for (int et = 0; et < 4; ++et) {
    const float ob = obias[et * 16 + l15] * (1.0f / N_);
#pragma unroll
    for (int r = 0; r < 4; ++r)
      out[((size_t)b * N_ + row0 + w * 16 + g * 4 + r) * 64 + et * 16 + l15] =
          acc2[et][r] * (1.0f / MT_SCALE) + ob;
  }
}

// ---------------- launch ----------------
extern "C" void kernel_launch(void* const* d_in, const int* in_sizes, int n_in,
                              void* d_out, int out_size, void* d_ws, size_t ws_size,
                              hipStream_t stream) {
  const float* v     = (const float*)d_in[0];
  const float* Wq_w  = (const float*)d_in[1];
  const float* Wq_b  = (const float*)d_in[2];
  const float* Wk_w  = (const float*)d_in[3];
  const float* Wk_b  = (const float*)d_in[4];
  const float* Wv_w  = (const float*)d_in[5];
  const float* Wv_b  = (const float*)d_in[6];
  const float* lnq_w = (const float*)d_in[7];
  const float* lnq_b = (const float*)d_in[8];
  const float* lnk_w = (const float*)d_in[9];
  const float* lnk_b = (const float*)d_in[10];
  const float* o_w   = (const float*)d_in[11];
  const float* o_b   = (const float*)d_in[12];
  float* out = (float*)d_out;
  char* ws = (char*)d_ws;
  if (ws_size < WS_NEED) return;

  _Float16* vb   = (_Float16*)(ws + OFF_V);
  _Float16* wqb  = (_Float16*)(ws + OFF_WQ);
  _Float16* wkb  = (_Float16*)(ws + OFF_WK);
  _Float16* wvb  = (_Float16*)(ws + OFF_WV);
  _Float16* Mt   = (_Float16*)(ws + OFF_MT);
  float*    KVg  = (float*)(ws + OFF_KVG);
  float*    part = (float*)(ws + OFF_PART);

  const int NTOT4 = B_ * N_ * CIN_ / 4 + 3 * (HD_ * CIN_ / 4);  // 548864
  prep_cast<<<NTOT4 / 256, 256, 0, stream>>>(v, Wq_w, Wk_w, Wv_w, vb, wqb, wkb, wvb);
  k1_kv<<<dim3(NCW_ / 4, H_, B_), 256, 0, stream>>>(vb, wkb, wvb, Wk_b, Wv_b, lnk_w, lnk_b, part);
  k2a_reduce<<<dim3(16, H_, B_), 256, 0, stream>>>(part, KVg);
  k2b_mt<<<dim3(4, H_, B_), 256, 0, stream>>>(KVg, o_w, Mt);
  k3_out<<<dim3(N_ / 64, B_), 256, 0, stream>>>(vb, wqb, Wq_b, lnq_w, lnq_b, Mt, o_b, out);
}

// Round 11
// 64.914 us; speedup vs baseline: 1.1175x; 1.1175x over previous
//
#include <hip/hip_runtime.h>
#include <hip/hip_bf16.h>

#define B_   4
#define N_   8192
#define CIN_ 64
#define H_   8
#define HD_  512
#define EPS_ 1e-5f
#define NCW_ 32            // wave-tasks per (b,h): 32 chunks x 256 rows
#define MT_SCALE 1024.0f   // power-of-2: keeps fp16 Mt away from subnormals

typedef _Float16 f16x8 __attribute__((ext_vector_type(8)));
typedef _Float16 f16x4 __attribute__((ext_vector_type(4)));
typedef float    f32x4 __attribute__((ext_vector_type(4)));

// ---------------- workspace layout ----------------
constexpr size_t OFF_V    = 0;
constexpr size_t SZ_V     = (size_t)B_ * N_ * CIN_ * 2;           // 4 MB f16 v
constexpr size_t OFF_WQ   = OFF_V + SZ_V;
constexpr size_t SZ_W     = (size_t)HD_ * CIN_ * 2;               // 64 KB each
constexpr size_t OFF_WK   = OFF_WQ + SZ_W;
constexpr size_t OFF_WV   = OFF_WK + SZ_W;
constexpr size_t OFF_MT   = OFF_WV + SZ_W;
constexpr size_t SZ_MT    = (size_t)B_ * 64 * HD_ * 2;            // 256 KB f16 Mt
constexpr size_t OFF_KVG  = OFF_MT + SZ_MT;
constexpr size_t SZ_KVG   = (size_t)B_ * H_ * 4096 * 4;           // 512 KB fp32
constexpr size_t OFF_PART = OFF_KVG + SZ_KVG;
constexpr size_t SZ_PART  = (size_t)B_ * H_ * NCW_ * 4096 * 4;    // 16 MB fp32
constexpr size_t WS_NEED  = OFF_PART + SZ_PART;

// ---------------- prep: all fp32->fp16 casts in one kernel ----------------
__global__ __launch_bounds__(256) void prep_cast(
    const float* __restrict__ v, const float* __restrict__ wq,
    const float* __restrict__ wk, const float* __restrict__ wv,
    _Float16* __restrict__ vb, _Float16* __restrict__ wqb,
    _Float16* __restrict__ wkb, _Float16* __restrict__ wvb) {
  const int NV4 = B_ * N_ * CIN_ / 4;   // 524288
  const int NW4 = HD_ * CIN_ / 4;       // 8192
  int i = blockIdx.x * 256 + threadIdx.x;  // grid sized exactly
  const float* src; _Float16* dst; int j;
  if (i < NV4)                { src = v;  dst = vb;  j = i; }
  else if (i < NV4 + NW4)     { src = wq; dst = wqb; j = i - NV4; }
  else if (i < NV4 + 2 * NW4) { src = wk; dst = wkb; j = i - NV4 - NW4; }
  else                        { src = wv; dst = wvb; j = i - NV4 - 2 * NW4; }
  const float4 f = reinterpret_cast<const float4*>(src)[j];
  f16x4 o;
  o[0] = (_Float16)f.x; o[1] = (_Float16)f.y; o[2] = (_Float16)f.z; o[3] = (_Float16)f.w;
  reinterpret_cast<f16x4*>(dst)[j] = o;
}

// ---------------- K1: INDEPENDENT waves (R9-proven), 4 tiles/wave ------------
// Each wave: own 18432B LDS region, own 256-row chunk (4 tiles of 64), writes
// its OWN partial. No cross-wave data sharing at all.
__global__ __launch_bounds__(256, 2) void k1_kv(
    const _Float16* __restrict__ vb, const _Float16* __restrict__ wkb,
    const _Float16* __restrict__ wvb, const float* __restrict__ kbias,
    const float* __restrict__ vbias, const float* __restrict__ lnkw,
    const float* __restrict__ lnkb, float* __restrict__ part) {
  const int ch = blockIdx.x, h = blockIdx.y, b = blockIdx.z;
  const int tid = threadIdx.x, w = tid >> 6, lane = tid & 63;
  const int l15 = lane & 15, g = lane >> 4;
  __shared__ alignas(16) char smem[73728];
  _Float16 (*Kt)[72] = reinterpret_cast<_Float16(*)[72]>(smem + w * 18432);        // [d][n]
  _Float16 (*Vt)[72] = reinterpret_cast<_Float16(*)[72]>(smem + w * 18432 + 9216); // [e][n]
  const int cw = ch * 4 + w;  // wave task 0..31

  const f32x4 z4 = {0.f, 0.f, 0.f, 0.f};
  f32x4 kv[4][4];
#pragma unroll
  for (int i = 0; i < 4; ++i)
#pragma unroll
    for (int j = 0; j < 4; ++j) kv[i][j] = z4;

  float kb[4], vbi[4], lw[4], lb[4];
#pragma unroll
  for (int c = 0; c < 4; ++c) {
    const int col = h * 64 + c * 16 + l15;
    kb[c] = kbias[col]; vbi[c] = vbias[col];
    lw[c] = lnkw[col];  lb[c] = lnkb[col];
  }
  f16x8 wkf[4][2], wvf[4][2];
#pragma unroll
  for (int c = 0; c < 4; ++c)
#pragma unroll
    for (int kk = 0; kk < 2; ++kk) {
      wkf[c][kk] = *reinterpret_cast<const f16x8*>(
          wkb + (size_t)(h * 64 + c * 16 + l15) * CIN_ + kk * 32 + g * 8);
      wvf[c][kk] = *reinterpret_cast<const f16x8*>(
          wvb + (size_t)(h * 64 + c * 16 + l15) * CIN_ + kk * 32 + g * 8);
    }

  for (int t = 0; t < 4; ++t) {
    const int row0 = cw * 256 + t * 64;
    f16x8 av[4][2];
#pragma unroll
    for (int m = 0; m < 4; ++m)
#pragma unroll
      for (int kk = 0; kk < 2; ++kk)
        av[m][kk] = *reinterpret_cast<const f16x8*>(
            vb + ((size_t)b * N_ + row0 + m * 16 + l15) * CIN_ + kk * 32 + g * 8);

    // ---- K proj + bias + LN -> Kt (m-pairs to cap VGPR) ----
#pragma unroll
    for (int mp = 0; mp < 2; ++mp) {
      f32x4 acc[2][4];
#pragma unroll
      for (int mi = 0; mi < 2; ++mi)
#pragma unroll
        for (int c = 0; c < 4; ++c) {
          f32x4 a = z4;
          a = __builtin_amdgcn_mfma_f32_16x16x32_f16(av[mp * 2 + mi][0], wkf[c][0], a, 0, 0, 0);
          a = __builtin_amdgcn_mfma_f32_16x16x32_f16(av[mp * 2 + mi][1], wkf[c][1], a, 0, 0, 0);
          acc[mi][c] = a;
        }
#pragma unroll
      for (int mi = 0; mi < 2; ++mi) {
        const int m = mp * 2 + mi;
        float s[4] = {0, 0, 0, 0}, ss[4] = {0, 0, 0, 0};
#pragma unroll
        for (int c = 0; c < 4; ++c)
#pragma unroll
          for (int r = 0; r < 4; ++r) {
            float x = acc[mi][c][r] + kb[c];
            acc[mi][c][r] = x;
            s[r] += x; ss[r] += x * x;
          }
#pragma unroll
        for (int r = 0; r < 4; ++r) {
#pragma unroll
          for (int off = 1; off < 16; off <<= 1) {
            s[r]  += __shfl_xor(s[r], off);
            ss[r] += __shfl_xor(ss[r], off);
          }
          const float mu   = s[r] * (1.f / 64.f);
          const float var  = ss[r] * (1.f / 64.f) - mu * mu;
          const float rstd = rsqrtf(var + EPS_);
#pragma unroll
          for (int c = 0; c < 4; ++c)
            acc[mi][c][r] = (acc[mi][c][r] - mu) * rstd * lw[c] + lb[c];
        }
#pragma unroll
        for (int c = 0; c < 4; ++c) {
          f16x4 p;
#pragma unroll
          for (int r = 0; r < 4; ++r) p[r] = (_Float16)acc[mi][c][r];
          *reinterpret_cast<f16x4*>(&Kt[c * 16 + l15][m * 16 + g * 4]) = p;
        }
      }
    }
    // ---- V proj + bias -> Vt ----
#pragma unroll
    for (int mp = 0; mp < 2; ++mp) {
      f32x4 acc[2][4];
#pragma unroll
      for (int mi = 0; mi < 2; ++mi)
#pragma unroll
        for (int c = 0; c < 4; ++c) {
          f32x4 a = z4;
          a = __builtin_amdgcn_mfma_f32_16x16x32_f16(av[mp * 2 + mi][0], wvf[c][0], a, 0, 0, 0);
          a = __builtin_amdgcn_mfma_f32_16x16x32_f16(av[mp * 2 + mi][1], wvf[c][1], a, 0, 0, 0);
          acc[mi][c] = a;
        }
#pragma unroll
      for (int mi = 0; mi < 2; ++mi) {
        const int m = mp * 2 + mi;
#pragma unroll
        for (int c = 0; c < 4; ++c) {
          f16x4 p;
#pragma unroll
          for (int r = 0; r < 4; ++r) p[r] = (_Float16)(acc[mi][c][r] + vbi[c]);
          *reinterpret_cast<f16x4*>(&Vt[c * 16 + l15][m * 16 + g * 4]) = p;
        }
      }
    }

    __syncthreads();  // LDS writes -> reads (own-wave data; barrier for ordering)

    // ---- KV accumulate (reads ONLY this wave's Kt/Vt) ----
    f16x8 va[4][2];
#pragma unroll
    for (int et = 0; et < 4; ++et)
#pragma unroll
      for (int nk = 0; nk < 2; ++nk)
        va[et][nk] = *reinterpret_cast<const f16x8*>(&Vt[et * 16 + l15][nk * 32 + g * 8]);
#pragma unroll
    for (int dt = 0; dt < 4; ++dt) {
      f16x8 ka[2];
#pragma unroll
      for (int nk = 0; nk < 2; ++nk)
        ka[nk] = *reinterpret_cast<const f16x8*>(&Kt[dt * 16 + l15][nk * 32 + g * 8]);
#pragma unroll
      for (int et = 0; et < 4; ++et) {
        kv[dt][et] = __builtin_amdgcn_mfma_f32_16x16x32_f16(ka[0], va[et][0], kv[dt][et], 0, 0, 0);
        kv[dt][et] = __builtin_amdgcn_mfma_f32_16x16x32_f16(ka[1], va[et][1], kv[dt][et], 0, 0, 0);
      }
    }

    __syncthreads();  // reads drained before next t's writes
  }

  // ---- per-wave partial store, [d][e] layout (R1/R9 exact) ----
  float* p0 = part + (size_t)((b * H_ + h) * NCW_ + cw) * 4096;
#pragma unroll
  for (int dt = 0; dt < 4; ++dt)
#pragma unroll
    for (int et = 0; et < 4; ++et)
#pragma unroll
      for (int r = 0; r < 4; ++r)
        p0[(dt * 16 + g * 4 + r) * 64 + et * 16 + l15] = kv[dt][et][r];
}

// ---------------- K2a: parallel tree-reduce partials -> KVg ----------------
__global__ __launch_bounds__(256) void k2a_reduce(const float* __restrict__ part,
                                                 float* __restrict__ KVg) {
  const int s = blockIdx.x, h = blockIdx.y, b = blockIdx.z;  // s: 0..15
  const int idx = s * 256 + threadIdx.x;
  const float* p0 = part + (size_t)((b * H_ + h) * NCW_) * 4096 + idx;
  float acc = 0.f;
#pragma unroll 8
  for (int ch = 0; ch < NCW_; ++ch) acc += p0[(size_t)ch * 4096];
  KVg[(size_t)(b * H_ + h) * 4096 + idx] = acc;
}

// ---- K2b: Mt[b][E][h*64+d] = MT_SCALE*(KV @ ow_h^T)[d,E]/N  (f16) ----------
__global__ __launch_bounds__(256) void k2b_mt(const float* __restrict__ KVg,
                                              const float* __restrict__ ow,
                                              _Float16* __restrict__ Mt) {
  const int z = blockIdx.x, h = blockIdx.y, b = blockIdx.z;  // z: 16-row E-slice
  const int tid = threadIdx.x;
  __shared__ float KV[4096];       // [d][e]
  __shared__ float OW[16][65];
  const float* kv0 = KVg + (size_t)(b * H_ + h) * 4096;
  for (int i = tid; i < 4096; i += 256) KV[i] = kv0[i];
  for (int i = tid; i < 16 * 64; i += 256) {
    int E = i >> 6, c = i & 63;
    OW[E][c] = ow[(size_t)(z * 16 + E) * HD_ + h * 64 + c];
  }
  __syncthreads();
  for (int i = tid; i < 1024; i += 256) {
    const int d = i >> 4, e = i & 15;
    float s = 0.f;
#pragma unroll
    for (int c = 0; c < 64; ++c) s += KV[d * 64 + c] * OW[e][c];
    Mt[(size_t)(b * 64 + z * 16 + e) * HD_ + h * 64 + d] =
        (_Float16)(s * (MT_SCALE / N_));
  }
}

// ---------------- K3: out = LN(Q) @ Mt^T + o_b/N (R9 orientation) -----------
// Phase 2 change vs R9: wave w owns output col-tile et=w for ALL 64 rows;
// its 16 Mt B-frags are hoisted into VGPRs BEFORE the barrier (latency
// overlapped with other waves' LN); inner loop is pure ds_read+MFMA.
__global__ __launch_bounds__(256, 2) void k3_out(
    const _Float16* __restrict__ vb, const _Float16* __restrict__ wqb,
    const float* __restrict__ qbias, const float* __restrict__ lnqw,
    const float* __restrict__ lnqb, const _Float16* __restrict__ Mt,
    const float* __restrict__ obias, float* __restrict__ out) {
  const int nt = blockIdx.x, b = blockIdx.y;
  const int tid = threadIdx.x, w = tid >> 6, lane = tid & 63;
  const int l15 = lane & 15, g = lane >> 4;
  __shared__ _Float16 Qt[64][520];  // [n][j]
  const int row0 = nt * 64;
  const f32x4 z4 = {0.f, 0.f, 0.f, 0.f};

  // v as A-frags: lane = n-row, k = cin contiguous (normal orientation)
  f16x8 av[4][2];
#pragma unroll
  for (int m = 0; m < 4; ++m)
#pragma unroll
    for (int kk = 0; kk < 2; ++kk)
      av[m][kk] = *reinterpret_cast<const f16x8*>(
          vb + ((size_t)b * N_ + row0 + m * 16 + l15) * CIN_ + kk * 32 + g * 8);

#pragma unroll
  for (int hh = 0; hh < 2; ++hh) {
    const int h = w * 2 + hh;
    f16x8 bf[4][2];  // Wq rows as B-frags
#pragma unroll
    for (int c = 0; c < 4; ++c)
#pragma unroll
      for (int kk = 0; kk < 2; ++kk)
        bf[c][kk] = *reinterpret_cast<const f16x8*>(
            wqb + (size_t)(h * 64 + c * 16 + l15) * CIN_ + kk * 32 + g * 8);
    float qb[4], lw[4], lb[4];
#pragma unroll
    for (int c = 0; c < 4; ++c) {
      const int col = h * 64 + c * 16 + l15;
      qb[c] = qbias[col]; lw[c] = lnqw[col]; lb[c] = lnqb[col];
    }
    f32x4 acc[4][4];
#pragma unroll
    for (int m = 0; m < 4; ++m)
#pragma unroll
      for (int c = 0; c < 4; ++c) {
        f32x4 a = z4;
        a = __builtin_amdgcn_mfma_f32_16x16x32_f16(av[m][0], bf[c][0], a, 0, 0, 0);
        a = __builtin_amdgcn_mfma_f32_16x16x32_f16(av[m][1], bf[c][1], a, 0, 0, 0);
        acc[m][c] = a;
      }
    // bias + LN over j (own 4 c-values + 16-lane butterfly), per row n
#pragma unroll
    for (int m = 0; m < 4; ++m) {
      float s[4] = {0, 0, 0, 0}, ss[4] = {0, 0, 0, 0};
#pragma unroll
      for (int c = 0; c < 4; ++c)
#pragma unroll
        for (int r = 0; r < 4; ++r) {
          float x = acc[m][c][r] + qb[c];
          acc[m][c][r] = x;
          s[r] += x; ss[r] += x * x;
        }
#pragma unroll
      for (int r = 0; r < 4; ++r) {
#pragma unroll
        for (int off = 1; off < 16; off <<= 1) {
          s[r]  += __shfl_xor(s[r], off);
          ss[r] += __shfl_xor(ss[r], off);
        }
        const float mu   = s[r] * (1.f / 64.f);
        const float var  = ss[r] * (1.f / 64.f) - mu * mu;
        const float rstd = rsqrtf(var + EPS_);
#pragma unroll
        for (int c = 0; c < 4; ++c)
          acc[m][c][r] = (acc[m][c][r] - mu) * rstd * lw[c] + lb[c];
      }
#pragma unroll
      for (int c = 0; c < 4; ++c)
#pragma unroll
        for (int r = 0; r < 4; ++r)
          Qt[m * 16 + g * 4 + r][h * 64 + c * 16 + l15] = (_Float16)acc[m][c][r];
    }
  }

  // hoist this wave's 16 Mt B-frags (col-tile E = w*16..w*16+15) pre-barrier
  f16x8 bm[16];
  {
    const size_t mb = (size_t)(b * 64 + w * 16 + l15) * HD_ + g * 8;
#pragma unroll
    for (int kk = 0; kk < 16; ++kk)
      bm[kk] = *reinterpret_cast<const f16x8*>(Mt + mb + kk * 32);
  }
  __syncthreads();

  // final GEMM: out[64 x 16] per wave = Qt[64 x 512] @ Mt[E-tile]^T
  f32x4 acc2[4];
#pragma unroll
  for (int m = 0; m < 4; ++m) acc2[m] = z4;
#pragma unroll
  for (int kk = 0; kk < 16; ++kk) {
#pragma unroll
    for (int m = 0; m < 4; ++m) {
      f16x8 aq = *reinterpret_cast<const f16x8*>(&Qt[m * 16 + l15][kk * 32 + g * 8]);
      acc2[m] = __builtin_amdgcn_mfma_f32_16x16x32_f16(aq, bm[kk], acc2[m], 0, 0, 0);
    }
  }
  const float ob = obias[w * 16 + l15] * (1.0f / N_);
#pragma unroll
  for (int m = 0; m < 4; ++m)
#pragma unroll
    for (int r = 0; r < 4; ++r)
      out[((size_t)b * N_ + row0 + m * 16 + g * 4 + r) * 64 + w * 16 + l15] =
          acc2[m][r] * (1.0f / MT_SCALE) + ob;
}

// ---------------- launch ----------------
extern "C" void kernel_launch(void* const* d_in, const int* in_sizes, int n_in,
                              void* d_out, int out_size, void* d_ws, size_t ws_size,
                              hipStream_t stream) {
  const float* v     = (const float*)d_in[0];
  const float* Wq_w  = (const float*)d_in[1];
  const float* Wq_b  = (const float*)d_in[2];
  const float* Wk_w  = (const float*)d_in[3];
  const float* Wk_b  = (const float*)d_in[4];
  const float* Wv_w  = (const float*)d_in[5];
  const float* Wv_b  = (const float*)d_in[6];
  const float* lnq_w = (const float*)d_in[7];
  const float* lnq_b = (const float*)d_in[8];
  const float* lnk_w = (const float*)d_in[9];
  const float* lnk_b = (const float*)d_in[10];
  const float* o_w   = (const float*)d_in[11];
  const float* o_b   = (const float*)d_in[12];
  float* out = (float*)d_out;
  char* ws = (char*)d_ws;
  if (ws_size < WS_NEED) return;

  _Float16* vb   = (_Float16*)(ws + OFF_V);
  _Float16* wqb  = (_Float16*)(ws + OFF_WQ);
  _Float16* wkb  = (_Float16*)(ws + OFF_WK);
  _Float16* wvb  = (_Float16*)(ws + OFF_WV);
  _Float16* Mt   = (_Float16*)(ws + OFF_MT);
  float*    KVg  = (float*)(ws + OFF_KVG);
  float*    part = (float*)(ws + OFF_PART);

  const int NTOT4 = B_ * N_ * CIN_ / 4 + 3 * (HD_ * CIN_ / 4);  // 548864
  prep_cast<<<NTOT4 / 256, 256, 0, stream>>>(v, Wq_w, Wk_w, Wv_w, vb, wqb, wkb, wvb);
  k1_kv<<<dim3(NCW_ / 4, H_, B_), 256, 0, stream>>>(vb, wkb, wvb, Wk_b, Wv_b, lnk_w, lnk_b, part);
  k2a_reduce<<<dim3(16, H_, B_), 256, 0, stream>>>(part, KVg);
  k2b_mt<<<dim3(4, H_, B_), 256, 0, stream>>>(KVg, o_w, Mt);
  k3_out<<<dim3(N_ / 64, B_), 256, 0, stream>>>(vb, wqb, Wq_b, lnq_w, lnq_b, Mt, o_b, out);
}